// Round 1
// baseline (8755.211 us; speedup 1.0000x reference)
//
#include <hip/hip_runtime.h>
#include <hip/hip_bf16.h>
#include <stdint.h>
#include <string.h>

// ---------------- problem constants ----------------
// B=64, T=256, D=H=256, L=50, O=2; K = 2H = 512 (concat [h_in; h_prev]); G = 4H = 1024
#define NB   64
#define NT   256
#define NH   256
#define NL   50
#define NK   512
#define NG   1024

typedef __attribute__((ext_vector_type(8)))  short   short8;
typedef __attribute__((ext_vector_type(8)))  __bf16  bf16x8;
typedef __attribute__((ext_vector_type(4)))  float   float4v;

__device__ __forceinline__ unsigned short f2bf(float f) {
  union { float f; uint32_t u; } v; v.f = f;
  uint32_t u = v.u;
  uint32_t r = (u + 0x7FFFu + ((u >> 16) & 1u)) >> 16;   // RNE
  return (unsigned short)r;
}
__device__ __forceinline__ float bf2f(unsigned short s) {
  union { uint32_t u; float f; } v; v.u = ((uint32_t)s) << 16;
  return v.f;
}
__device__ __forceinline__ float sigmoidf_(float x) { return 1.0f / (1.0f + expf(-x)); }

// ---------------- workspace layout (bytes) ----------------
// Wswz : 50*1024*512 bf16 = 52,428,800
// Bias : 50*1024 f32      =    204,800
// Xbf  : 256*64*256 bf16  =  8,388,608   ([t][b][d])
// Hbuf : 2*50*64*256 bf16 =  3,276,800   (parity, layer)
// Cst  : 50*64*256 f32    =  3,276,800
// Y    : 256*64*256 bf16  =  8,388,608   ([t][b][h], layer-49 h)
#define OFF_WSWZ 0
#define OFF_BIAS 52428800
#define OFF_XBF  52633600
#define OFF_HBUF 61022208
#define OFF_CST  64299008
#define OFF_Y    67575808
// total: 75,964,416 bytes

// ---------------- preprocessing ----------------
// Weight swizzle: Wswz[idx], idx = ((((l*16+c)*4+q)*16+kt)*64+lam)*8+j
// holds Wcat[g = q*256 + c*16 + (lam&15)][k = kt*32 + (lam>>4)*8 + j] as bf16,
// where Wcat = [W_ih | W_hh] along k. This is the exact MFMA B-fragment lane
// order, so the main loop's B loads are 16B/lane fully coalesced.
__global__ void prep_w(const float* __restrict__ Wih, const float* __restrict__ Whh,
                       unsigned short* __restrict__ Wswz) {
  int idx = blockIdx.x * 256 + threadIdx.x;        // 26,214,400 total
  int j   = idx & 7;
  int lam = (idx >> 3) & 63;
  int kt  = (idx >> 9) & 15;
  int q   = (idx >> 13) & 3;
  int c   = (idx >> 15) & 15;
  int l   = idx >> 19;
  int k   = kt * 32 + (lam >> 4) * 8 + j;
  int g   = q * 256 + c * 16 + (lam & 15);
  float v = (k < 256) ? Wih[(l * NG + g) * 256 + k]
                      : Whh[(l * NG + g) * 256 + (k - 256)];
  Wswz[idx] = f2bf(v);
}

// Bias permuted to chunk order: Bias[l*1024 + c*64 + q*16 + col] = bih+bhh at g=q*256+c*16+col
__global__ void prep_bias(const float* __restrict__ bih, const float* __restrict__ bhh,
                          float* __restrict__ Bias) {
  int idx = blockIdx.x * 256 + threadIdx.x;        // 51,200 total
  int col = idx & 15; int q = (idx >> 4) & 3; int c = (idx >> 6) & 15; int l = idx >> 10;
  int g = q * 256 + c * 16 + col;
  Bias[idx] = bih[l * NG + g] + bhh[l * NG + g];
}

// x [b][t][d] f32 -> Xbf [t][b][d] bf16
__global__ void prep_x(const float* __restrict__ x, unsigned short* __restrict__ Xbf) {
  int idx = blockIdx.x * 256 + threadIdx.x;        // 4,194,304 total
  int d = idx & 255; int t = (idx >> 8) & 255; int b = idx >> 16;
  Xbf[(t * NB + b) * 256 + d] = f2bf(x[idx]);
}

// ---------------- diagonal cell kernel ----------------
// diag k: cells (l, t=k-l). Grid fixed at 200 WGs: blockIdx>>2 = layer (stable
// XCD mapping for L2 weight residency), blockIdx&3 = quarter of the 16 gate-chunks.
// Each WG: stage h_cat[64][512] bf16 in LDS (XOR-swizzled, 64KB), then 4 waves
// each compute one 64-gate chunk = {i,f,g,o} x 16 hidden units via 256 MFMAs.
__global__ __launch_bounds__(256) void cell_kernel(
    int diag,
    const unsigned short* __restrict__ Wswz,
    const float* __restrict__ Bias,
    const unsigned short* __restrict__ Xbf,
    unsigned short* __restrict__ Hbuf,
    float* __restrict__ Cst,
    unsigned short* __restrict__ Y) {
  int l = blockIdx.x >> 2;
  int t = diag - l;
  if (t < 0 || t >= NT) return;
  int w   = blockIdx.x & 3;
  int tid = threadIdx.x;

  __shared__ unsigned short hc[64 * 512];   // 64 KB, unit=8bf16, phys = b*64 + (ku ^ (b&7))

  int p  = diag & 1;
  bool t0 = (t == 0);
  const unsigned short* In = (l == 0) ? (Xbf + t * (NB * 256))
                                      : (Hbuf + ((p * NL + (l - 1)) * NB) * 256);
  const unsigned short* Pv = Hbuf + ((p * NL + l) * NB) * 256;

  // stage 64x512 bf16 (4096 units of 8): 16 units/thread, coalesced 16B loads
  for (int i = 0; i < 16; ++i) {
    int u  = i * 256 + tid;
    int b  = u >> 6;
    int ku = u & 63;
    int k  = ku * 8;
    short8 val;
    if (k < 256)       val = *(const short8*)(In + b * 256 + k);
    else if (!t0)      val = *(const short8*)(Pv + b * 256 + (k - 256));
    else               val = short8{0, 0, 0, 0, 0, 0, 0, 0};
    *(short8*)(hc + (b * 64 + (ku ^ (b & 7))) * 8) = val;
  }
  __syncthreads();

  int wave = tid >> 6;
  int lane = tid & 63;
  int c    = w * 4 + wave;          // chunk 0..15 -> hidden units [c*16, c*16+16)
  int colg = lane & 15;
  int quad = lane >> 4;

  float4v acc[4][4];
  const float* bp = Bias + l * NG + c * 64;
#pragma unroll
  for (int q = 0; q < 4; ++q) {
    float bv = bp[q * 16 + colg];
    float4v f4 = {bv, bv, bv, bv};
#pragma unroll
    for (int m = 0; m < 4; ++m) acc[m][q] = f4;
  }

  const unsigned short* wp = Wswz + (size_t)(l * 16 + c) * 32768 + lane * 8;

#pragma unroll 2
  for (int kt = 0; kt < 16; ++kt) {
    bf16x8 a[4];
#pragma unroll
    for (int m = 0; m < 4; ++m) {
      int row = m * 16 + colg;
      int ku  = (kt * 4 + quad) ^ (colg & 7);    // row&7 == colg&7
      a[m] = *(const bf16x8*)(hc + (row * 64 + ku) * 8);
    }
    bf16x8 bfr[4];
#pragma unroll
    for (int q = 0; q < 4; ++q)
      bfr[q] = *(const bf16x8*)(wp + (q * 16 + kt) * 512);
#pragma unroll
    for (int m = 0; m < 4; ++m)
#pragma unroll
      for (int q = 0; q < 4; ++q)
        acc[m][q] = __builtin_amdgcn_mfma_f32_16x16x32_bf16(a[m], bfr[q], acc[m][q], 0, 0, 0);
  }

  // epilogue: C/D layout col=lane&15 (gate col), row=quad*4+reg (batch)
  int j  = c * 16 + colg;
  int pw = (diag + 1) & 1;
  unsigned short* Hout = Hbuf + ((pw * NL + l) * NB) * 256;
  float* crow = Cst + (l * NB) * 256;
#pragma unroll
  for (int m = 0; m < 4; ++m) {
#pragma unroll
    for (int r = 0; r < 4; ++r) {
      int b = m * 16 + quad * 4 + r;
      float gi = sigmoidf_(acc[m][0][r]);
      float gf = sigmoidf_(acc[m][1][r]);
      float gg = tanhf(acc[m][2][r]);
      float go = sigmoidf_(acc[m][3][r]);
      float cold = t0 ? 0.0f : crow[b * 256 + j];
      float cn = gf * cold + gi * gg;
      crow[b * 256 + j] = cn;
      float h = go * tanhf(cn);
      unsigned short hb = f2bf(h);
      Hout[b * 256 + j] = hb;
      if (l == NL - 1) Y[(t * NB + b) * 256 + j] = hb;
    }
  }
}

// ---------------- final projection ----------------
// out[b][t][o] = sigmoid(sum_h Y[t][b][h] * Wout[o][h] + bout[o])
__global__ void final_proj(const unsigned short* __restrict__ Y,
                           const float* __restrict__ Wout,
                           const float* __restrict__ bout,
                           float* __restrict__ out) {
  int t = blockIdx.x;
  int tid = threadIdx.x;            // 128 = 64 b * 2 o
  int b = tid >> 1, o = tid & 1;
  const unsigned short* yrow = Y + (t * NB + b) * 256;
  const float* wr = Wout + o * 256;
  float s = bout[o];
  for (int k = 0; k < 256; ++k) s += bf2f(yrow[k]) * wr[k];
  out[(b * NT + t) * 2 + o] = sigmoidf_(s);
}

extern "C" void kernel_launch(void* const* d_in, const int* in_sizes, int n_in,
                              void* d_out, int out_size, void* d_ws, size_t ws_size,
                              hipStream_t stream) {
  (void)in_sizes; (void)n_in; (void)out_size; (void)ws_size;
  const float* x    = (const float*)d_in[0];
  const float* Wih  = (const float*)d_in[1];
  const float* Whh  = (const float*)d_in[2];
  const float* bih  = (const float*)d_in[3];
  const float* bhh  = (const float*)d_in[4];
  const float* Wout = (const float*)d_in[5];
  const float* bout = (const float*)d_in[6];
  float* out = (float*)d_out;

  char* ws = (char*)d_ws;
  unsigned short* Wswz = (unsigned short*)(ws + OFF_WSWZ);
  float*          Bias = (float*)(ws + OFF_BIAS);
  unsigned short* Xbf  = (unsigned short*)(ws + OFF_XBF);
  unsigned short* Hbuf = (unsigned short*)(ws + OFF_HBUF);
  float*          Cst  = (float*)(ws + OFF_CST);
  unsigned short* Y    = (unsigned short*)(ws + OFF_Y);

  prep_w   <<<102400, 256, 0, stream>>>(Wih, Whh, Wswz);
  prep_bias<<<200,    256, 0, stream>>>(bih, bhh, Bias);
  prep_x   <<<16384,  256, 0, stream>>>(x, Xbf);

  // anti-diagonal wavefront: diag k holds cells (l, t=k-l); all deps are from diag k-1,
  // so back-to-back kernel launches on the stream provide the needed barrier.
  for (int k = 0; k < NT + NL - 1; ++k)
    cell_kernel<<<NL * 4, 256, 0, stream>>>(k, Wswz, Bias, Xbf, Hbuf, Cst, Y);

  final_proj<<<NT, 128, 0, stream>>>(Y, Wout, bout, out);
}